// Round 19
// baseline (401.538 us; speedup 1.0000x reference)
//
#include <hip/hip_runtime.h>
#include <hip/hip_fp8.h>

#define S_LEN 512
#define BATCH 256
#define L 128
#define PAD_ID 0
#define START_ID 1

typedef int    i32x8 __attribute__((ext_vector_type(8)));
typedef int    i32x4 __attribute__((ext_vector_type(4)));
typedef float  f32x4 __attribute__((ext_vector_type(4)));
typedef unsigned int   u32x4 __attribute__((ext_vector_type(4)));
typedef unsigned short u16x2 __attribute__((ext_vector_type(2)));

__device__ __forceinline__ unsigned int umax2(unsigned int a, unsigned int b) {
    u16x2 x = __builtin_bit_cast(u16x2, a), y = __builtin_bit_cast(u16x2, b);
#if defined(__has_builtin) && __has_builtin(__builtin_elementwise_max)
    return __builtin_bit_cast(unsigned int, __builtin_elementwise_max(x, y));  // v_pk_max_u16
#else
    u16x2 r; r.x = x.x > y.x ? x.x : y.x; r.y = x.y > y.y ? x.y : y.y;
    return __builtin_bit_cast(unsigned int, r);
#endif
}
// NaN-killing sanitizer (fmaxf(NaN,lo)=lo on AMD): result always in [lo,hi], never NaN.
__device__ __forceinline__ float sane(float x, float lo, float hi) {
    return fminf(fmaxf(x, lo), hi);
}
__device__ __forceinline__ unsigned short f2bf(float f) {   // RNE f32->bf16
    unsigned int u = __builtin_bit_cast(unsigned int, f);
    return (unsigned short)((u + 0x7fffu + ((u >> 16) & 1u)) >> 16);
}
// pack 4 f32 -> 4 fp8 e4m3 bytes in one dword (2 cvt_pk: lo half then hi half via opsel)
__device__ __forceinline__ int pk4(float a, float b, float c, float d) {
#if defined(__has_builtin) && __has_builtin(__builtin_amdgcn_cvt_pk_fp8_f32)
    int lo = __builtin_amdgcn_cvt_pk_fp8_f32(a, b, 0, false);
    return __builtin_amdgcn_cvt_pk_fp8_f32(c, d, lo, true);
#else
    __hip_fp8_e4m3 A(a), B(b), C(c), D(d);
    return (int)A.__x | ((int)B.__x << 8) | ((int)C.__x << 16) | ((int)D.__x << 24);
#endif
}
// exact max byte (u8) over 8 dwords of positive-e4m3 bytes, via even/odd u16 lanes
__device__ __forceinline__ unsigned int bmax8(u32x4 a, u32x4 b) {
    const unsigned int M = 0x00FF00FFu;
    unsigned int l0 = umax2(a.x & M, a.y & M), l1 = umax2(a.z & M, a.w & M);
    unsigned int l2 = umax2(b.x & M, b.y & M), l3 = umax2(b.z & M, b.w & M);
    unsigned int h0 = umax2((a.x >> 8) & M, (a.y >> 8) & M);
    unsigned int h1 = umax2((a.z >> 8) & M, (a.w >> 8) & M);
    unsigned int h2 = umax2((b.x >> 8) & M, (b.y >> 8) & M);
    unsigned int h3 = umax2((b.z >> 8) & M, (b.w >> 8) & M);
    unsigned int v = umax2(umax2(umax2(l0, l1), umax2(l2, l3)),
                           umax2(umax2(h0, h1), umax2(h2, h3)));
    u16x2 t = __builtin_bit_cast(u16x2, v);
    return (unsigned int)(t.x > t.y ? t.x : t.y);
}
__device__ __forceinline__ float fp8dec(unsigned int bb) {   // e4m3 byte -> float
    bb &= 0x7Fu;
    int e = (int)(bb >> 3), mt = (int)(bb & 7u);
    float v = e ? __builtin_ldexpf((float)(8 + mt), e - 10)
                : __builtin_ldexpf((float)mt, -9);
    return sane(v, 1e-9f, 448.f);
}
__device__ __forceinline__ f32x4 vexp4(f32x4 x) {
    f32x4 r;
    r.x = __expf(x.x); r.y = __expf(x.y); r.z = __expf(x.z); r.w = __expf(x.w);
    return r;
}
__device__ __forceinline__ f32x4 vmin4(f32x4 a, float c) {
    f32x4 r;
    r.x = fminf(a.x, c); r.y = fminf(a.y, c); r.z = fminf(a.z, c); r.w = fminf(a.w, c);
    return r;
}
// two bf16-pair dwords (+packed exponent adjust) -> f32x4 {lo0,hi0,lo1,hi1}
__device__ __forceinline__ f32x4 xpair(int w0, int w1, u16x2 adj) {
    u16x2 a = __builtin_bit_cast(u16x2, w0) - adj;   // v_pk_sub_u16: exponent -= e7
    u16x2 c = __builtin_bit_cast(u16x2, w1) - adj;
    unsigned ua = __builtin_bit_cast(unsigned, a), uc = __builtin_bit_cast(unsigned, c);
    f32x4 r;
    r.x = __builtin_bit_cast(float, ua << 16);
    r.y = __builtin_bit_cast(float, ua & 0xffff0000u);
    r.z = __builtin_bit_cast(float, uc << 16);
    r.w = __builtin_bit_cast(float, uc & 0xffff0000u);
    return r;
}

// ws layout: qf[256][128] fp8 | qb[256][128] fp8 | Sf[256] f32 | Sb[256] f32 | n[256] i32 | exp-table bf16
#define WS_QF 0
#define WS_QB 32768
#define WS_SF 65536
#define WS_SB 66560
#define WS_N  67584
#define WS_TAB 68864                                    // 256-aligned, after n[256]
#define TAB_BYTES ((size_t)S_LEN * BATCH * L * 2)       // 33,554,432

// prefix-ones length of row b, with byte/f32 mask-encoding self-detect (first 8KB scan).
__device__ __forceinline__ int compute_len(const void* masks, int b, int lane) {
    const unsigned int* mw0 = (const unsigned int*)masks;
    int pred = 0;
    #pragma unroll
    for (int k = 0; k < 32; ++k) {
        unsigned int w0 = mw0[lane + 64 * k];
        pred |= (w0 > 1u && w0 != 0x3f800000u);
    }
    const bool isbyte = (__ballot(pred) != 0ull);
    int cnt = 0;
    if (isbyte) {
        const unsigned int* mw = mw0 + b * (S_LEN / 4);
        #pragma unroll
        for (int k = 0; k < 2; ++k) {
            unsigned int w0 = mw[lane + 64 * k];
            cnt += ((w0 & 0xffu) != 0) + ((w0 & 0xff00u) != 0) +
                   ((w0 & 0xff0000u) != 0) + ((w0 & 0xff000000u) != 0);
        }
    } else {
        const unsigned int* mw = mw0 + b * S_LEN;
        #pragma unroll
        for (int k = 0; k < 8; ++k) cnt += (mw[lane + 64 * k] != 0u);
    }
    #pragma unroll
    for (int off = 32; off; off >>= 1) cnt += __shfl_xor(cnt, off, 64);
    return cnt;
}

__device__ __forceinline__ void gold_block(
        const float* __restrict__ emit, const int* __restrict__ labels,
        const void* __restrict__ masks, const float* __restrict__ T,
        float* __restrict__ out, int b, int lane) {
    const int len = compute_len(masks, b, lane);
    float gsum = 0.f;
    for (int tt = lane; tt < len; tt += 64) {
        int nxt = labels[b * S_LEN + tt];
        int prv = tt ? labels[b * S_LEN + tt - 1] : START_ID;
        gsum += emit[((size_t)tt * BATCH + b) * L + nxt] + T[prv * L + nxt];
        if (tt == len - 1) gsum += T[nxt * L + PAD_ID];
    }
    #pragma unroll
    for (int off = 32; off; off >>= 1) gsum += __shfl_xor(gsum, off, 64);
    if (lane == 0) atomicAdd(out, -gsum);
}

// ---- pre-pass: tab[(row*256+b)*4+g][t][y] = bf16(exp(emit[row][b][16t+4g+y])) ----
// Lane-swizzled so each scan lane's 32 values are one contiguous 64B block.
__global__ __launch_bounds__(256, 4) void k_pre(
        const float* __restrict__ emit, unsigned char* __restrict__ tab) {
    const int N4 = S_LEN * BATCH * 32;                 // dword-pair units
    int o = blockIdx.x * 256 + threadIdx.x;
    const int stride = gridDim.x * 256;
    for (; o < N4; o += stride) {
        int base = o >> 5, t = o & 7, g = (o >> 3) & 3;
        f32x4 v = *(const f32x4*)(emit + ((size_t)base << 7) + 16 * t + 4 * g);
        f32x4 e = vexp4(v);
        unsigned d0 = (unsigned)f2bf(e.x) | ((unsigned)f2bf(e.y) << 16);
        unsigned d1 = (unsigned)f2bf(e.z) | ((unsigned)f2bf(e.w) << 16);
        uint2 pr; pr.x = d0; pr.y = d1;
        *(uint2*)(tab + (size_t)o * 8) = pr;
    }
}

// r16 (resubmit — r18 bench was an infra failure). DUAL-CHAIN waves.
// r15b measured 205us (~1930 cy/step, VGPR 168, only -9% vs r14 despite
// removing scratch+exp): fits cy/step ~ 1050 + 4.5*VALU — pure latency-bound;
// 768 waves on 1024 SIMDs = <=1 wave/SIMD, nothing hides dependent latency.
// Fix: one wave interleaves TWO same-dir chains of different batches (Af
// depends only on dir+T, shared for free). Two independent step-DAGs in one
// basic block let the scheduler fill each chain's stalls with the other's
// instrs. Tail imbalance via wave-uniform ternary commits.
// Blocks 0..127: fwd pairs (2bp,2bp+1); 128..255: bwd pairs; 256..511: gold.
__global__ __launch_bounds__(64, 1) void k_scan_tab2(
        const float* __restrict__ emit, const int* __restrict__ labels,
        const void* __restrict__ masks, const float* __restrict__ T,
        unsigned char* __restrict__ ws, float* __restrict__ out) {
    const int bid  = blockIdx.x;
    const int lane = threadIdx.x;

    if (bid >= 2 * (BATCH / 2)) { gold_block(emit, labels, masks, T, out, bid - 2 * (BATCH / 2), lane); return; }

    const int dir = bid >> 7;             // 0 = forward, 1 = backward
    const int bp  = bid & 127;
    const int b0  = 2 * bp, b1 = 2 * bp + 1;
    const int g = lane >> 4, m = lane & 15;

    const int len0 = compute_len(masks, b0, lane);
    const int len1 = compute_len(masks, b1, lane);
    const int nn0 = len0 - 1, nn1 = len1 - 1;
    const int kf0 = nn0 / 2, kf1 = nn1 / 2;
    int steps0 = dir ? (nn0 - kf0 - 1) : kf0;
    int steps1 = dir ? (nn1 - kf1 - 1) : kf1;
    if (steps0 < 0) steps0 = 0;
    if (steps1 < 0) steps1 = 0;
    const bool active0 = (dir == 0) || (nn0 >= 1);
    const bool active1 = (dir == 0) || (nn1 >= 1);
    const int mxs = steps0 > steps1 ? steps0 : steps1;

    // ---- A-fragments: E rows in f8f6f4 swizzled layout (row = m, byte->k).
    //      Depends only on dir and T — SHARED by both chains. ----
    i32x8 Af[8];
    #pragma unroll
    for (int t = 0; t < 8; ++t) {
        #pragma unroll
        for (int d = 0; d < 8; ++d) {
            float v[4];
            #pragma unroll
            for (int y = 0; y < 4; ++y) {
                int sl = 4 * d + y;
                int k  = 16 * (sl & 7) + 4 * g + (sl >> 3);
                int idx = dir ? ((16 * t + m) * L + k) : (k * L + 16 * t + m);
                v[y] = __expf(T[idx]);
            }
            Af[t][d] = pk4(v[0], v[1], v[2], v[3]);
        }
    }

    // ---- init both states in registers (same math as r15b, per chain) ----
    float Sbase0, Sbase1;
    i32x8 Aq0, Aq1;
#define INITC(AQ, SB, BB, NN)                                                      \
    {                                                                              \
        int rr = dir ? ((NN) > 0 ? (NN) : 0) : 0;                                  \
        f32x4 fv[8];                                                               \
        const float* e0 = emit + ((size_t)rr * BATCH + (BB)) * L;                  \
        _Pragma("unroll")                                                          \
        for (int t = 0; t < 8; ++t) {                                              \
            int k0 = 16 * t + 4 * g;                                               \
            f32x4 ev4 = *(const f32x4*)(e0 + k0);                                  \
            f32x4 tv;                                                              \
            if (dir == 0) {                                                        \
                tv = *(const f32x4*)(T + START_ID * L + k0);                       \
            } else {                                                               \
                tv.x = T[(k0 + 0) * L + PAD_ID];                                   \
                tv.y = T[(k0 + 1) * L + PAD_ID];                                   \
                tv.z = T[(k0 + 2) * L + PAD_ID];                                   \
                tv.w = T[(k0 + 3) * L + PAD_ID];                                   \
            }                                                                      \
            fv[t] = ev4 + tv;                                                      \
        }                                                                          \
        float mloc = -1e30f;                                                       \
        _Pragma("unroll")                                                          \
        for (int t = 0; t < 8; ++t)                                                \
            mloc = fmaxf(mloc, fmaxf(fmaxf(fv[t].x, fv[t].y),                      \
                                     fmaxf(fv[t].z, fv[t].w)));                    \
        mloc = fmaxf(mloc, __shfl_xor(mloc, 16, 64));                              \
        mloc = fmaxf(mloc, __shfl_xor(mloc, 32, 64));                              \
        SB = mloc;                                                                 \
        f32x4 pv[8];                                                               \
        _Pragma("unroll")                                                          \
        for (int t = 0; t < 8; ++t) pv[t] = vexp4(fv[t] - SB);                     \
        AQ[0] = pk4(pv[0].x, pv[1].x, pv[2].x, pv[3].x);                           \
        AQ[1] = pk4(pv[4].x, pv[5].x, pv[6].x, pv[7].x);                           \
        AQ[2] = pk4(pv[0].y, pv[1].y, pv[2].y, pv[3].y);                           \
        AQ[3] = pk4(pv[4].y, pv[5].y, pv[6].y, pv[7].y);                           \
        AQ[4] = pk4(pv[0].z, pv[1].z, pv[2].z, pv[3].z);                           \
        AQ[5] = pk4(pv[4].z, pv[5].z, pv[6].z, pv[7].z);                           \
        AQ[6] = pk4(pv[0].w, pv[1].w, pv[2].w, pv[3].w);                           \
        AQ[7] = pk4(pv[4].w, pv[5].w, pv[6].w, pv[7].w);                           \
    }
    INITC(Aq0, Sbase0, b0, nn0)
    INITC(Aq1, Sbase1, b1, nn1)
#undef INITC

    int Se0 = 0, Se1 = 0;
    const f32x4 z = {0.f, 0.f, 0.f, 0.f};
    const unsigned char* tab = ws + WS_TAB;

    if (mxs > 0) {
        i32x4 c0w0, c0w1, c0w2, c0w3, c0v0, c0v1, c0v2, c0v3;
        i32x4 c1w0, c1w1, c1w2, c1w3, c1v0, c1v1, c1v2, c1v3;

#define LOADC(W0, W1, W2, W3, BB, NN, SS, idx)                                     \
        {                                                                          \
            int ii = (idx) < (SS) ? (idx) : (SS) - 1;                              \
            if (ii < 0) ii = 0;                                                    \
            int row = dir ? ((NN) - 1 - ii) : (1 + ii);                            \
            if (row < 0) row = 0;                                                  \
            const i32x4* tp = (const i32x4*)(tab +                                 \
                (((size_t)(row * BATCH + (BB))) << 8) + (g << 6));                 \
            W0 = tp[0]; W1 = tp[1]; W2 = tp[2]; W3 = tp[3];                        \
        }

#define MFS2(AQ, AT) __builtin_amdgcn_mfma_scale_f32_16x16x128_f8f6f4((AT), (AQ), z, 0, 0, 0, 127, 0, 127)
#define STEPC(AQ, SE, GO, W0, W1, W2, W3)                                          \
        {                                                                          \
            f32x4 d0 = MFS2(AQ, Af[0]), d1 = MFS2(AQ, Af[1]);                      \
            f32x4 d2 = MFS2(AQ, Af[2]), d3 = MFS2(AQ, Af[3]);                      \
            f32x4 d4 = MFS2(AQ, Af[4]), d5 = MFS2(AQ, Af[5]);                      \
            f32x4 d6 = MFS2(AQ, Af[6]), d7 = MFS2(AQ, Af[7]);                      \
            u32x4 qlo = {(unsigned)AQ[0], (unsigned)AQ[1],                         \
                         (unsigned)AQ[2], (unsigned)AQ[3]};                        \
            u32x4 qhi = {(unsigned)AQ[4], (unsigned)AQ[5],                         \
                         (unsigned)AQ[6], (unsigned)AQ[7]};                        \
            unsigned int qm = bmax8(qlo, qhi);                                     \
            {                                                                      \
                unsigned int q2 = (unsigned int)__shfl_xor((int)qm, 16, 64);       \
                qm = qm > q2 ? qm : q2;                                            \
                q2 = (unsigned int)__shfl_xor((int)qm, 32, 64);                    \
                qm = qm > q2 ? qm : q2;                                            \
            }                                                                      \
            int e7 = (int)(qm >> 3) - 7;                                           \
            SE += (GO) ? e7 : 0;                                                   \
            unsigned short as_ = (unsigned short)(e7 << 7);                        \
            u16x2 adj; adj.x = as_; adj.y = as_;                                   \
            f32x4 x0 = xpair((W0).x, (W0).y, adj);                                 \
            f32x4 x1 = xpair((W0).z, (W0).w, adj);                                 \
            f32x4 x2 = xpair((W1).x, (W1).y, adj);                                 \
            f32x4 x3 = xpair((W1).z, (W1).w, adj);                                 \
            f32x4 x4 = xpair((W2).x, (W2).y, adj);                                 \
            f32x4 x5 = xpair((W2).z, (W2).w, adj);                                 \
            f32x4 x6 = xpair((W3).x, (W3).y, adj);                                 \
            f32x4 x7 = xpair((W3).z, (W3).w, adj);                                 \
            f32x4 p0 = vmin4(d0 * x0, 448.f), p1 = vmin4(d1 * x1, 448.f);          \
            f32x4 p2 = vmin4(d2 * x2, 448.f), p3 = vmin4(d3 * x3, 448.f);          \
            f32x4 p4 = vmin4(d4 * x4, 448.f), p5 = vmin4(d5 * x5, 448.f);          \
            f32x4 p6 = vmin4(d6 * x6, 448.f), p7 = vmin4(d7 * x7, 448.f);          \
            int q0_ = pk4(p0.x, p1.x, p2.x, p3.x);                                 \
            int q1_ = pk4(p4.x, p5.x, p6.x, p7.x);                                 \
            int q2_ = pk4(p0.y, p1.y, p2.y, p3.y);                                 \
            int q3_ = pk4(p4.y, p5.y, p6.y, p7.y);                                 \
            int q4_ = pk4(p0.z, p1.z, p2.z, p3.z);                                 \
            int q5_ = pk4(p4.z, p5.z, p6.z, p7.z);                                 \
            int q6_ = pk4(p0.w, p1.w, p2.w, p3.w);                                 \
            int q7_ = pk4(p4.w, p5.w, p6.w, p7.w);                                 \
            AQ[0] = (GO) ? q0_ : AQ[0]; AQ[1] = (GO) ? q1_ : AQ[1];                \
            AQ[2] = (GO) ? q2_ : AQ[2]; AQ[3] = (GO) ? q3_ : AQ[3];                \
            AQ[4] = (GO) ? q4_ : AQ[4]; AQ[5] = (GO) ? q5_ : AQ[5];                \
            AQ[6] = (GO) ? q6_ : AQ[6]; AQ[7] = (GO) ? q7_ : AQ[7];                \
        }

        LOADC(c0w0, c0w1, c0w2, c0w3, b0, nn0, steps0, 0)
        LOADC(c1w0, c1w1, c1w2, c1w3, b1, nn1, steps1, 0)
        LOADC(c0v0, c0v1, c0v2, c0v3, b0, nn0, steps0, 1)
        LOADC(c1v0, c1v1, c1v2, c1v3, b1, nn1, steps1, 1)
        int i = 0;
        bool go0, go1;
        for (;;) {
            go0 = i < steps0; go1 = i < steps1;
            STEPC(Aq0, Se0, go0, c0w0, c0w1, c0w2, c0w3)
            STEPC(Aq1, Se1, go1, c1w0, c1w1, c1w2, c1w3)
            if (++i == mxs) break;
            LOADC(c0w0, c0w1, c0w2, c0w3, b0, nn0, steps0, i + 1)
            LOADC(c1w0, c1w1, c1w2, c1w3, b1, nn1, steps1, i + 1)
            go0 = i < steps0; go1 = i < steps1;
            STEPC(Aq0, Se0, go0, c0v0, c0v1, c0v2, c0v3)
            STEPC(Aq1, Se1, go1, c1v0, c1v1, c1v2, c1v3)
            if (++i == mxs) break;
            LOADC(c0v0, c0v1, c0v2, c0v3, b0, nn0, steps0, i + 1)
            LOADC(c1v0, c1v1, c1v2, c1v3, b1, nn1, steps1, i + 1)
        }
#undef STEPC
#undef MFS2
#undef LOADC
    }

    // ---- seam + scale to ws (byte order identical to r15b: slot s holds q[k(s)]) ----
    if (m == 0) {
        if (active0) {
            i32x4* sp = (i32x4*)(ws + (dir ? WS_QB : WS_QF) + b0 * L + 32 * g);
            sp[0] = (i32x4){Aq0[0], Aq0[1], Aq0[2], Aq0[3]};
            sp[1] = (i32x4){Aq0[4], Aq0[5], Aq0[6], Aq0[7]};
        }
        if (active1) {
            i32x4* sp = (i32x4*)(ws + (dir ? WS_QB : WS_QF) + b1 * L + 32 * g);
            sp[0] = (i32x4){Aq1[0], Aq1[1], Aq1[2], Aq1[3]};
            sp[1] = (i32x4){Aq1[4], Aq1[5], Aq1[6], Aq1[7]};
        }
    }
    if (lane == 0) {
        float* Sarr = (float*)(ws + (dir ? WS_SB : WS_SF));
        if (active0) Sarr[b0] = Sbase0 + 0.69314718f * (float)Se0;
        if (active1) Sarr[b1] = Sbase1 + 0.69314718f * (float)Se1;
        if (dir == 0) {
            ((int*)(ws + WS_N))[b0] = nn0;
            ((int*)(ws + WS_N))[b1] = nn1;
        }
    }
}

// Fallback (ws too small for the table): verbatim r14 path — known-passing.
__global__ __launch_bounds__(64, 1) void k_scan_f32(
        const float* __restrict__ emit, const int* __restrict__ labels,
        const void* __restrict__ masks, const float* __restrict__ T,
        unsigned char* __restrict__ ws, float* __restrict__ out) {
    const int bid  = blockIdx.x;
    const int lane = threadIdx.x;

    if (bid >= 2 * BATCH) { gold_block(emit, labels, masks, T, out, bid - 2 * BATCH, lane); return; }

    const int b   = bid & (BATCH - 1);
    const int dir = bid >> 8;
    const int g = lane >> 4, m = lane & 15;

    const int len = compute_len(masks, b, lane);
    const int n  = len - 1;
    const int kf = n / 2;
    const int nB = n - kf - 1;
    const int steps = dir ? (nB > 0 ? nB : 0) : kf;
    if (dir == 1 && n < 1) return;

    i32x8 Af[8];
    #pragma unroll
    for (int t = 0; t < 8; ++t) {
        #pragma unroll
        for (int d = 0; d < 8; ++d) {
            float v[4];
            #pragma unroll
            for (int y = 0; y < 4; ++y) {
                int sl = 4 * d + y;
                int k  = 16 * (sl & 7) + 4 * g + (sl >> 3);
                int idx = dir ? ((16 * t + m) * L + k) : (k * L + 16 * t + m);
                v[y] = __expf(T[idx]);
            }
            Af[t][d] = pk4(v[0], v[1], v[2], v[3]);
        }
    }

    float S_base;
    i32x8 Aq;
    {
        f32x4 fv[8];
        const float* e0 = emit + (dir ? ((size_t)n * BATCH + b) * L : (size_t)b * L);
        #pragma unroll
        for (int t = 0; t < 8; ++t) {
            int k0 = 16 * t + 4 * g;
            f32x4 ev4 = *(const f32x4*)(e0 + k0);
            f32x4 tv;
            if (dir == 0) {
                tv = *(const f32x4*)(T + START_ID * L + k0);
            } else {
                tv.x = T[(k0 + 0) * L + PAD_ID];
                tv.y = T[(k0 + 1) * L + PAD_ID];
                tv.z = T[(k0 + 2) * L + PAD_ID];
                tv.w = T[(k0 + 3) * L + PAD_ID];
            }
            fv[t] = ev4 + tv;
        }
        float mx = -1e30f;
        #pragma unroll
        for (int t = 0; t < 8; ++t)
            mx = fmaxf(mx, fmaxf(fmaxf(fv[t].x, fv[t].y), fmaxf(fv[t].z, fv[t].w)));
        mx = fmaxf(mx, __shfl_xor(mx, 16, 64));
        mx = fmaxf(mx, __shfl_xor(mx, 32, 64));
        S_base = mx;
        f32x4 pv[8];
        #pragma unroll
        for (int t = 0; t < 8; ++t) pv[t] = vexp4(fv[t] - S_base);
        Aq[0] = pk4(pv[0].x, pv[1].x, pv[2].x, pv[3].x);
        Aq[1] = pk4(pv[4].x, pv[5].x, pv[6].x, pv[7].x);
        Aq[2] = pk4(pv[0].y, pv[1].y, pv[2].y, pv[3].y);
        Aq[3] = pk4(pv[4].y, pv[5].y, pv[6].y, pv[7].y);
        Aq[4] = pk4(pv[0].z, pv[1].z, pv[2].z, pv[3].z);
        Aq[5] = pk4(pv[4].z, pv[5].z, pv[6].z, pv[7].z);
        Aq[6] = pk4(pv[0].w, pv[1].w, pv[2].w, pv[3].w);
        Aq[7] = pk4(pv[4].w, pv[5].w, pv[6].w, pv[7].w);
    }

    int Se = 0;
    const f32x4 z = {0.f, 0.f, 0.f, 0.f};

    if (steps > 0) {
        auto ldrow8 = [&](int idx, f32x4* dst) {
            int ii  = idx < steps ? idx : steps - 1;
            int row = dir ? (n - 1 - ii) : (1 + ii);
            const float* ep = emit + ((size_t)row * BATCH + b) * L + 4 * g;
            #pragma unroll
            for (int t = 0; t < 8; ++t) dst[t] = *(const f32x4*)(ep + 16 * t);
        };
        f32x4 ea[8], eb[8], ec[8];
        ldrow8(0, ea); ldrow8(1, eb); ldrow8(2, ec);
        int i = 0;

#define MFS(AT) __builtin_amdgcn_mfma_scale_f32_16x16x128_f8f6f4((AT), Aq, z, 0, 0, 0, 127, 0, 127)
#define STEP(EB)                                                                   \
        {                                                                          \
            f32x4 d0 = MFS(Af[0]), d1 = MFS(Af[1]), d2 = MFS(Af[2]), d3 = MFS(Af[3]); \
            f32x4 d4 = MFS(Af[4]), d5 = MFS(Af[5]), d6 = MFS(Af[6]), d7 = MFS(Af[7]); \
            f32x4 x0 = vexp4(EB[0]), x1 = vexp4(EB[1]), x2 = vexp4(EB[2]),         \
                  x3 = vexp4(EB[3]), x4 = vexp4(EB[4]), x5 = vexp4(EB[5]),         \
                  x6 = vexp4(EB[6]), x7 = vexp4(EB[7]);                            \
            u32x4 qlo = {(unsigned)Aq[0], (unsigned)Aq[1],                         \
                         (unsigned)Aq[2], (unsigned)Aq[3]};                        \
            u32x4 qhi = {(unsigned)Aq[4], (unsigned)Aq[5],                         \
                         (unsigned)Aq[6], (unsigned)Aq[7]};                        \
            unsigned int qm = bmax8(qlo, qhi);                                     \
            {                                                                      \
                unsigned int q2 = (unsigned int)__shfl_xor((int)qm, 16, 64);       \
                qm = qm > q2 ? qm : q2;                                            \
                q2 = (unsigned int)__shfl_xor((int)qm, 32, 64);                    \
                qm = qm > q2 ? qm : q2;                                            \
            }                                                                      \
            int e7 = (int)(qm >> 3) - 7;                                           \
            Se += e7;                                                              \
            float kk = __builtin_bit_cast(float, (unsigned int)(127 - e7) << 23);  \
            x0 *= kk; x1 *= kk; x2 *= kk; x3 *= kk;                                \
            x4 *= kk; x5 *= kk; x6 *= kk; x7 *= kk;                                \
            f32x4 p0 = vmin4(d0 * x0, 448.f), p1 = vmin4(d1 * x1, 448.f);          \
            f32x4 p2 = vmin4(d2 * x2, 448.f), p3 = vmin4(d3 * x3, 448.f);          \
            f32x4 p4 = vmin4(d4 * x4, 448.f), p5 = vmin4(d5 * x5, 448.f);          \
            f32x4 p6 = vmin4(d6 * x6, 448.f), p7 = vmin4(d7 * x7, 448.f);          \
            Aq[0] = pk4(p0.x, p1.x, p2.x, p3.x);                                   \
            Aq[1] = pk4(p4.x, p5.x, p6.x, p7.x);                                   \
            Aq[2] = pk4(p0.y, p1.y, p2.y, p3.y);                                   \
            Aq[3] = pk4(p4.y, p5.y, p6.y, p7.y);                                   \
            Aq[4] = pk4(p0.z, p1.z, p2.z, p3.z);                                   \
            Aq[5] = pk4(p4.z, p5.z, p6.z, p7.z);                                   \
            Aq[6] = pk4(p0.w, p1.w, p2.w, p3.w);                                   \
            Aq[7] = pk4(p4.w, p5.w, p6.w, p7.w);                                   \
        }

        for (;;) {
            STEP(ea); if (++i == steps) break; ldrow8(i + 2, ea);
            STEP(eb); if (++i == steps) break; ldrow8(i + 2, eb);
            STEP(ec); if (++i == steps) break; ldrow8(i + 2, ec);
        }
#undef STEP
#undef MFS
    }

    if (m == 0) {
        i32x4* sp = (i32x4*)(ws + (dir ? WS_QB : WS_QF) + b * L + 32 * g);
        sp[0] = (i32x4){Aq[0], Aq[1], Aq[2], Aq[3]};
        sp[1] = (i32x4){Aq[4], Aq[5], Aq[6], Aq[7]};
    }
    if (lane == 0) {
        ((float*)(ws + (dir ? WS_SB : WS_SF)))[b] = S_base + 0.69314718f * (float)Se;
        if (dir == 0) ((int*)(ws + WS_N))[b] = n;
    }
}

// Exact-f32 join: enc_b = Sf + Sb + log(q_kf^T E u_{kf+1})  (n=0: Sf + log(q0.expTpad))
__global__ __launch_bounds__(64, 1) void k_join(
        const float* __restrict__ T, const unsigned char* __restrict__ ws,
        float* __restrict__ out) {
    const int b = blockIdx.x;
    const int lane = threadIdx.x;
    __shared__ float qsh[L], ush[L];

    const int n = ((const int*)(ws + WS_N))[b];
    #pragma unroll
    for (int k = 0; k < 2; ++k) {
        int s = lane + 64 * k;
        int j = 16 * (s & 7) + (s >> 3);
        qsh[j] = fp8dec(ws[WS_QF + b * L + s]);
        ush[j] = fp8dec(ws[WS_QB + b * L + s]);
    }
    __syncthreads();

    float ev = 0.f;
    if (n >= 1) {
        #pragma unroll
        for (int k = 0; k < 2; ++k) {
            int j = lane + 64 * k;
            float v0 = 0.f, v1 = 0.f, v2 = 0.f, v3 = 0.f;
            #pragma unroll 8
            for (int i = 0; i < L; i += 4) {
                v0 = fmaf(qsh[i + 0], __expf(T[(i + 0) * L + j]), v0);
                v1 = fmaf(qsh[i + 1], __expf(T[(i + 1) * L + j]), v1);
                v2 = fmaf(qsh[i + 2], __expf(T[(i + 2) * L + j]), v2);
                v3 = fmaf(qsh[i + 3], __expf(T[(i + 3) * L + j]), v3);
            }
            ev += ((v0 + v1) + (v2 + v3)) * ush[j];
        }
    } else {
        #pragma unroll
        for (int k = 0; k < 2; ++k) {
            int j = lane + 64 * k;
            ev += qsh[j] * __expf(T[j * L + PAD_ID]);
        }
    }
    #pragma unroll
    for (int off = 32; off; off >>= 1) ev += __shfl_xor(ev, off, 64);

    if (lane == 0) {
        float Sf = ((const float*)(ws + WS_SF))[b];
        float Sb = (n >= 1) ? ((const float*)(ws + WS_SB))[b] : 0.f;
        float enc = Sf + Sb + __logf(fmaxf(ev, 1e-35f));
        atomicAdd(out, sane(enc, -1e30f, 1e30f));
    }
}

extern "C" void kernel_launch(void* const* d_in, const int* in_sizes, int n_in,
                              void* d_out, int out_size, void* d_ws, size_t ws_size,
                              hipStream_t stream) {
    const float* emit   = (const float*)d_in[0];
    const int*   labels = (const int*)d_in[1];
    const void*  masks  = d_in[2];
    const float* T      = (const float*)d_in[3];
    float* out = (float*)d_out;
    unsigned char* ws = (unsigned char*)d_ws;

    hipMemsetAsync(d_out, 0, sizeof(float), stream);
    if (ws_size >= (size_t)WS_TAB + TAB_BYTES) {
        k_pre<<<dim3(4096), dim3(256), 0, stream>>>(emit, ws + WS_TAB);
        k_scan_tab2<<<dim3(2 * (BATCH / 2) + BATCH), dim3(64), 0, stream>>>(emit, labels, masks, T, ws, out);
    } else {
        k_scan_f32<<<dim3(3 * BATCH), dim3(64), 0, stream>>>(emit, labels, masks, T, ws, out);
    }
    k_join<<<dim3(BATCH), dim3(64), 0, stream>>>(T, ws, out);
}

// Round 20
// 216.148 us; speedup vs baseline: 1.8577x; 1.8577x over previous
//
#include <hip/hip_runtime.h>
#include <hip/hip_fp8.h>

#define S_LEN 512
#define BATCH 256
#define L 128
#define PAD_ID 0
#define START_ID 1

typedef int    i32x8 __attribute__((ext_vector_type(8)));
typedef int    i32x4 __attribute__((ext_vector_type(4)));
typedef float  f32x4 __attribute__((ext_vector_type(4)));
typedef unsigned int   u32x4 __attribute__((ext_vector_type(4)));
typedef unsigned short u16x2 __attribute__((ext_vector_type(2)));

__device__ __forceinline__ unsigned int umax2(unsigned int a, unsigned int b) {
    u16x2 x = __builtin_bit_cast(u16x2, a), y = __builtin_bit_cast(u16x2, b);
#if defined(__has_builtin) && __has_builtin(__builtin_elementwise_max)
    return __builtin_bit_cast(unsigned int, __builtin_elementwise_max(x, y));  // v_pk_max_u16
#else
    u16x2 r; r.x = x.x > y.x ? x.x : y.x; r.y = x.y > y.y ? x.y : y.y;
    return __builtin_bit_cast(unsigned int, r);
#endif
}
// NaN-killing sanitizer (fmaxf(NaN,lo)=lo on AMD): result always in [lo,hi], never NaN.
__device__ __forceinline__ float sane(float x, float lo, float hi) {
    return fminf(fmaxf(x, lo), hi);
}
__device__ __forceinline__ unsigned short f2bf(float f) {   // RNE f32->bf16
    unsigned int u = __builtin_bit_cast(unsigned int, f);
    return (unsigned short)((u + 0x7fffu + ((u >> 16) & 1u)) >> 16);
}
__device__ __forceinline__ float bf2f(unsigned short b) {
    return __builtin_bit_cast(float, (unsigned int)b << 16);
}
__device__ __forceinline__ int pk2_fp8(float a, float b) {
#if defined(__has_builtin) && __has_builtin(__builtin_amdgcn_cvt_pk_fp8_f32)
    return __builtin_amdgcn_cvt_pk_fp8_f32(a, b, 0, false);
#else
    __hip_fp8_e4m3 A(a), B(b);
    return (int)A.__x | ((int)B.__x << 8);
#endif
}
// exact max byte (u8) over 8 dwords of positive-e4m3 bytes, via even/odd u16 lanes
__device__ __forceinline__ unsigned int bmax8(u32x4 a, u32x4 b) {
    const unsigned int M = 0x00FF00FFu;
    unsigned int l0 = umax2(a.x & M, a.y & M), l1 = umax2(a.z & M, a.w & M);
    unsigned int l2 = umax2(b.x & M, b.y & M), l3 = umax2(b.z & M, b.w & M);
    unsigned int h0 = umax2((a.x >> 8) & M, (a.y >> 8) & M);
    unsigned int h1 = umax2((a.z >> 8) & M, (a.w >> 8) & M);
    unsigned int h2 = umax2((b.x >> 8) & M, (b.y >> 8) & M);
    unsigned int h3 = umax2((b.z >> 8) & M, (b.w >> 8) & M);
    unsigned int v = umax2(umax2(umax2(l0, l1), umax2(l2, l3)),
                           umax2(umax2(h0, h1), umax2(h2, h3)));
    u16x2 t = __builtin_bit_cast(u16x2, v);
    return (unsigned int)(t.x > t.y ? t.x : t.y);
}
__device__ __forceinline__ float fp8dec(unsigned int bb) {   // e4m3 byte -> float
    bb &= 0x7Fu;
    int e = (int)(bb >> 3), mt = (int)(bb & 7u);
    float v = e ? __builtin_ldexpf((float)(8 + mt), e - 10)
                : __builtin_ldexpf((float)mt, -9);
    return sane(v, 1e-9f, 448.f);
}

// ws layout: qf[256][128] fp8 | qb[256][128] fp8 | Sf[256] f32 | Sb[256] f32 | nArr[256] i32
#define WS_QF 0
#define WS_QB 32768
#define WS_SF 65536
#define WS_SB 66560
#define WS_N  67584

// r17: the proven r12 structure (140us k_scan, best measured; 4-wave blocks, 2
// MFMA/wave/step, LDS state, 2 chains/SIMD via co-residency) + two critical-path
// substitutions validated in r15b (passed, absmax 0.0):
// (a) staging stores bf16(exp(emit)) -> per-step xe = bf2f(elds) (no v_exp_f32
//     on the chain; the 2 expf move to the parallel staging loop);
// (b) exponent-only rescale: e7=(hd>>3)-7, kk=2^-e7 bitcast, integer Se+=e7,
//     final S += ln2*Se — removes fp8dec + v_rcp + v_log from the chain.
// All r13-r16 structural rewrites (153/226/205/297us) lost to r12's 140us:
// across-wave co-residency beats any manufactured in-wave ILP.
__global__ __launch_bounds__(256, 1) void k_scan2(
        const float* __restrict__ emit, const int* __restrict__ labels,
        const void* __restrict__ masks, const float* __restrict__ T,
        unsigned char* __restrict__ ws, float* __restrict__ out) {
    const int b   = blockIdx.x & (BATCH - 1);
    const int dir = blockIdx.x >> 8;         // 0 = forward, 1 = backward
    const int tid = threadIdx.x;
    const int w = tid >> 6;                  // wave 0..3
    const int lane = tid & 63;
    const int g = lane >> 4, m = lane & 15;  // quad (k-chunk), col
    const int ja = 32 * w + m, jb = ja + 16; // this wave's two output labels

    __shared__ unsigned short elds[255][L];              // bf16(exp(emit)) rows
    __shared__ __align__(16) unsigned char qs[2][L];     // state, double-buffered
    __shared__ __align__(8)  unsigned char hb[2][4];     // hint bytes [buf][quad]
    __shared__ float part[4];
    __shared__ float fsx[4];
    __shared__ int   ib[4];

    // ---- init block-shared state + mask encoding self-detect (first 8KB) ----
    {
        const unsigned int* mw0 = (const unsigned int*)masks;
        int pred = 0;
        #pragma unroll
        for (int k = 0; k < 8; ++k) {
            unsigned int w0 = mw0[tid + 256 * k];
            pred |= (w0 > 1u && w0 != 0x3f800000u);
        }
        unsigned long long bal = __ballot(pred);
        if (lane == 0) ib[w] = (bal != 0ull) ? 1 : 0;
        if (tid < 8)   ((unsigned char*)hb)[tid] = 0x38;   // fp8(1.0)
        if (tid < 256) ((unsigned char*)qs)[tid] = 0x38;   // both buffers = 1.0
        if (tid < 4)   { part[tid] = 0.f; fsx[tid] = 0.f; }
    }
    __syncthreads();
    const bool isbyte = (ib[0] | ib[1] | ib[2] | ib[3]) != 0;

    // ---- len of row b (prefix-ones mask; per-wave redundant, uniform) ----
    int len;
    {
        int cnt = 0;
        if (isbyte) {
            const unsigned int* mw = (const unsigned int*)masks + b * (S_LEN / 4);
            #pragma unroll
            for (int k = 0; k < 2; ++k) {
                unsigned int w0 = mw[lane + 64 * k];
                cnt += ((w0 & 0xffu) != 0) + ((w0 & 0xff00u) != 0) +
                       ((w0 & 0xff0000u) != 0) + ((w0 & 0xff000000u) != 0);
            }
        } else {
            const unsigned int* mw = (const unsigned int*)masks + b * S_LEN;
            #pragma unroll
            for (int k = 0; k < 8; ++k) cnt += (mw[lane + 64 * k] != 0u);
        }
        #pragma unroll
        for (int off = 32; off; off >>= 1) cnt += __shfl_xor(cnt, off, 64);
        len = cnt;
    }
    const int n  = len - 1;
    const int kf = n / 2;                    // forward steps
    const int nB = n - kf - 1;               // backward steps (may be <0 for n=0)
    const int steps = dir ? (nB > 0 ? nB : 0) : kf;

    // ---- B-frags: byte slot s = 32g+4d+y, j(s) = 16*(s&7)+(s>>3).
    //      forward (E^T matvec): B[s][col] = expT[j(s)][col]
    //      backward (E matvec):  B[s][col] = expT[col][j(s)] ----
#define LDBX(BF, nt, TR)                                                                     \
    {                                                                                        \
        _Pragma("unroll")                                                                    \
        for (int d = 0; d < 8; ++d) {                                                        \
            int s0 = 32 * g + 4 * d;                                                         \
            float v0, v1, v2, v3;                                                            \
            if (TR) {                                                                        \
                v0 = __expf(T[(16 * (nt) + m) * L + (16 * ((s0 + 0) & 7) + ((s0 + 0) >> 3))]); \
                v1 = __expf(T[(16 * (nt) + m) * L + (16 * ((s0 + 1) & 7) + ((s0 + 1) >> 3))]); \
                v2 = __expf(T[(16 * (nt) + m) * L + (16 * ((s0 + 2) & 7) + ((s0 + 2) >> 3))]); \
                v3 = __expf(T[(16 * (nt) + m) * L + (16 * ((s0 + 3) & 7) + ((s0 + 3) >> 3))]); \
            } else {                                                                         \
                v0 = __expf(T[(16 * ((s0 + 0) & 7) + ((s0 + 0) >> 3)) * L + 16 * (nt) + m]);   \
                v1 = __expf(T[(16 * ((s0 + 1) & 7) + ((s0 + 1) >> 3)) * L + 16 * (nt) + m]);   \
                v2 = __expf(T[(16 * ((s0 + 2) & 7) + ((s0 + 2) >> 3)) * L + 16 * (nt) + m]);   \
                v3 = __expf(T[(16 * ((s0 + 3) & 7) + ((s0 + 3) >> 3)) * L + 16 * (nt) + m]);   \
            }                                                                                \
            int p01 = pk2_fp8(v0, v1), p23 = pk2_fp8(v2, v3);                                \
            BF[d] = (p01 & 0xffff) | (p23 << 16);                                            \
        }                                                                                    \
    }
    i32x8 Bq0, Bq1;
    if (dir == 0) { LDBX(Bq0, 2 * w, 0) LDBX(Bq1, 2 * w + 1, 0) }
    else          { LDBX(Bq0, 2 * w, 1) LDBX(Bq1, 2 * w + 1, 1) }

    // ---- stage this dir's emit rows into LDS as bf16(EXP(emit)) (coalesced):
    //      forward: rows 1..kf -> slot r-1; backward: rows kf+1..n-1 -> slot r-(kf+1) ----
    for (int idx = tid; idx < steps * 64; idx += 256) {
        int rl = idx >> 6, c2 = (idx & 63) * 2;
        int row = dir ? (kf + 1 + rl) : (1 + rl);
        const float* ep = emit + ((size_t)row * BATCH + b) * L + c2;
        float e0 = __expf(ep[0]), e1 = __expf(ep[1]);
        *(unsigned int*)&elds[rl][c2] =
            (unsigned int)f2bf(e0) | ((unsigned int)f2bf(e1) << 16);
    }

    // ---- init state: fwd q0 (emit row 0); bwd u_n = x_n o w (emit row n, exact) ----
    float fa = 0.f, fbv = 0.f;
    const bool active = (dir == 0) || (n >= 1);
    if (dir == 0) {
        fa  = emit[b * L + ja] + T[START_ID * L + ja];
        fbv = emit[b * L + jb] + T[START_ID * L + jb];
    } else if (n >= 1) {
        fa  = emit[((size_t)n * BATCH + b) * L + ja] + T[ja * L + PAD_ID];
        fbv = emit[((size_t)n * BATCH + b) * L + jb] + T[jb * L + PAD_ID];
    }
    {
        float mx = fmaxf(fa, fbv);
        #pragma unroll
        for (int off = 32; off; off >>= 1) mx = fmaxf(mx, __shfl_xor(mx, off, 64));
        if (lane == 0) fsx[w] = mx;
    }
    __syncthreads();   // also makes staged emit visible
    float S = 0.f, p0 = 0.f, p1 = 0.f;
    int Se = 0;
    if (active) {
        S = fmaxf(fmaxf(fsx[0], fsx[1]), fmaxf(fsx[2], fsx[3]));
        p0 = sane(__expf(fa - S), 1e-9f, 400.f);
        p1 = sane(__expf(fbv - S), 1e-9f, 400.f);
        if (g == 0)
            *(short*)&qs[0][8 * m + 2 * w] = (short)(pk2_fp8(p0, p1) & 0xffff);
    }
    __syncthreads();

    // ---- hot loop (r12 step; exp-table xe + exponent-only rescale) ----
    const f32x4 z = {0.f, 0.f, 0.f, 0.f};
    for (int i = 0; i < steps; ++i) {
        const int rb = i & 1, wb2 = (i + 1) & 1;
        const int slot = dir ? (nB - 1 - i) : i;

        i32x4 alo = *(const i32x4*)&qs[rb][32 * g];
        i32x4 ahi = *(const i32x4*)&qs[rb][32 * g + 16];
        unsigned int hd = *(const unsigned int*)&hb[rb][0];
        float xe0 = bf2f(elds[slot][ja]);     // bf16(exp(emit)) -> f32: one shift
        float xe1 = bf2f(elds[slot][jb]);

        {   // uniform max of the 4 hint bytes (exact max of all 128 state bytes)
            const unsigned int M = 0x00FF00FFu;
            unsigned int v = umax2(hd & M, (hd >> 8) & M);
            u16x2 tv = __builtin_bit_cast(u16x2, v);
            hd = (unsigned int)(tv.x > tv.y ? tv.x : tv.y);
        }
        int e7 = (int)(hd >> 3) - 7;          // exponent-only rescale (r15b-validated)
        float kk = __builtin_bit_cast(float, (unsigned int)(127 - e7) << 23);

        i32x8 A;
        A[0] = alo[0]; A[1] = alo[1]; A[2] = alo[2]; A[3] = alo[3];
        A[4] = ahi[0]; A[5] = ahi[1]; A[6] = ahi[2]; A[7] = ahi[3];

        f32x4 c0 = __builtin_amdgcn_mfma_scale_f32_16x16x128_f8f6f4(A, Bq0, z, 0, 0, 0, 127, 0, 127);
        f32x4 c1 = __builtin_amdgcn_mfma_scale_f32_16x16x128_f8f6f4(A, Bq1, z, 0, 0, 0, 127, 0, 127);

        unsigned int qm = bmax8(__builtin_bit_cast(u32x4, alo),
                                __builtin_bit_cast(u32x4, ahi));
        if (w == 0 && m == 0) hb[wb2][g] = (unsigned char)(qm & 0x7Fu);

        p0 = sane(c0[0] * kk * xe0, 1e-9f, 400.f);   // rows replicated: c[0] valid
        p1 = sane(c1[0] * kk * xe1, 1e-9f, 400.f);
        if (g == 0)
            *(short*)&qs[wb2][8 * m + 2 * w] = (short)(pk2_fp8(p0, p1) & 0xffff);
        Se += e7;
        __syncthreads();
    }

    // ---- seam + scale to ws ----
    unsigned char* seam = ws + (dir ? WS_QB : WS_QF) + b * L;
    if (tid < 32) ((int*)seam)[tid] = ((const int*)qs[steps & 1])[tid];
    if (tid == 0) {
        ((float*)(ws + (dir ? WS_SB : WS_SF)))[b] = S + 0.69314718f * (float)Se;
        if (dir == 0) ((int*)(ws + WS_N))[b] = n;
    }

    // ---- gold (forward block only; exact f32) -> out ----
    if (dir == 0) {
        float gsum = 0.f;
        for (int tt = tid; tt < len; tt += 256) {
            int nxt = labels[b * S_LEN + tt];
            int prv = tt ? labels[b * S_LEN + tt - 1] : START_ID;
            gsum += emit[((size_t)tt * BATCH + b) * L + nxt] + T[prv * L + nxt];
            if (tt == len - 1) gsum += T[nxt * L + PAD_ID];
        }
        #pragma unroll
        for (int off = 32; off; off >>= 1) gsum += __shfl_xor(gsum, off, 64);
        if (lane == 0) part[w] = gsum;
        __syncthreads();
        if (tid == 0)
            atomicAdd(out, -((part[0] + part[1]) + (part[2] + part[3])));
    }
}

// Exact-f32 join: enc_b = Sf + Sb + log(q_kf^T E u_{kf+1})  (n=0: Sf + log(q0.expTpad))
__global__ __launch_bounds__(64, 1) void k_join(
        const float* __restrict__ T, const unsigned char* __restrict__ ws,
        float* __restrict__ out) {
    const int b = blockIdx.x;
    const int lane = threadIdx.x;
    __shared__ float qsh[L], ush[L];

    const int n = ((const int*)(ws + WS_N))[b];
    // decode seam bytes (store-order slot s -> label 16*(s&7)+(s>>3))
    #pragma unroll
    for (int k = 0; k < 2; ++k) {
        int s = lane + 64 * k;
        int j = 16 * (s & 7) + (s >> 3);
        qsh[j] = fp8dec(ws[WS_QF + b * L + s]);
        ush[j] = fp8dec(ws[WS_QB + b * L + s]);
    }
    __syncthreads();

    float ev = 0.f;
    if (n >= 1) {
        #pragma unroll
        for (int k = 0; k < 2; ++k) {
            int j = lane + 64 * k;
            float v = 0.f;
            for (int i = 0; i < L; ++i)
                v = fmaf(qsh[i], __expf(T[i * L + j]), v);
            ev += v * ush[j];
        }
    } else {
        #pragma unroll
        for (int k = 0; k < 2; ++k) {
            int j = lane + 64 * k;
            ev += qsh[j] * __expf(T[j * L + PAD_ID]);
        }
    }
    #pragma unroll
    for (int off = 32; off; off >>= 1) ev += __shfl_xor(ev, off, 64);

    if (lane == 0) {
        float Sf = ((const float*)(ws + WS_SF))[b];
        float Sb = (n >= 1) ? ((const float*)(ws + WS_SB))[b] : 0.f;
        float enc = Sf + Sb + __logf(fmaxf(ev, 1e-35f));
        atomicAdd(out, sane(enc, -1e30f, 1e30f));
    }
}

extern "C" void kernel_launch(void* const* d_in, const int* in_sizes, int n_in,
                              void* d_out, int out_size, void* d_ws, size_t ws_size,
                              hipStream_t stream) {
    const float* emit   = (const float*)d_in[0];
    const int*   labels = (const int*)d_in[1];
    const void*  masks  = d_in[2];
    const float* T      = (const float*)d_in[3];
    float* out = (float*)d_out;
    unsigned char* ws = (unsigned char*)d_ws;

    hipMemsetAsync(d_out, 0, sizeof(float), stream);
    k_scan2<<<dim3(2 * BATCH), dim3(256), 0, stream>>>(emit, labels, masks, T, ws, out);
    k_join <<<dim3(BATCH),     dim3(64),  0, stream>>>(T, ws, out);
}